// Round 1
// baseline (2018.278 us; speedup 1.0000x reference)
//
#include <hip/hip_runtime.h>
#include <math.h>

#define N 50000
#define E 600000
// channel dims
#define NS 64
#define NVC 32
#define A_DIM 16
#define GS 96

__device__ __forceinline__ float silu_f(float x) { return x / (1.f + __expf(-x)); }
__device__ __forceinline__ float sigm_f(float x) { return 1.f / (1.f + __expf(-x)); }

// ---------------- Kernel A: s1 = node_s@W1s/8 ; v1 = node_v x W1v /sqrt(32) ----------------
__global__ __launch_bounds__(256, 4)
void k_lin1(const float* __restrict__ node_s, const float* __restrict__ node_v,
            const float* __restrict__ W1s, const float* __restrict__ W1v,
            float* __restrict__ s1, float* __restrict__ v1) {
  __shared__ float w1s[64 * 64];
  __shared__ float w1v[32 * 32];
  for (int i = threadIdx.x; i < 64 * 64; i += 256) w1s[i] = W1s[i];
  for (int i = threadIdx.x; i < 32 * 32; i += 256) w1v[i] = W1v[i];
  __syncthreads();
  const float is_ns = 0.125f;                 // 1/sqrt(64)
  const float is_nv = 0.17677669529663689f;   // 1/sqrt(32)
  int gtid = blockIdx.x * 256 + threadIdx.x;
  int stride = gridDim.x * 256;
  for (int i = gtid; i < N * 160; i += stride) {
    int n = i / 160, ch = i % 160;
    if (ch < 64) {
      const float* row = node_s + n * 64;
      float acc = 0.f;
#pragma unroll
      for (int u = 0; u < 64; u++) acc += row[u] * w1s[u * 64 + ch];
      s1[n * 64 + ch] = acc * is_ns;
    } else {
      int p = ch - 64, v = p / 3, c = p % 3;
      const float* row = node_v + n * 96;
      float acc = 0.f;
#pragma unroll
      for (int u = 0; u < 32; u++) acc += row[u * 3 + c] * w1v[u * 32 + v];
      v1[n * 96 + p] = acc * is_nv;
    }
  }
}

// ---------------- Kernel B: per-edge message + scatter ----------------
// 8 edges per block pass. LDS: W2s 36864B + W2v 12288B + scratch -> ~62KB
__global__ __launch_bounds__(256, 2)
void k_edge(const float* __restrict__ s1, const float* __restrict__ v1,
            const float* __restrict__ emb, const float* __restrict__ sh0,
            const float* __restrict__ sh1, const int* __restrict__ eidx,
            const float* __restrict__ Wm1, const float* __restrict__ Wm2,
            const float* __restrict__ W2s, const float* __restrict__ W2v,
            float* __restrict__ aggs, float* __restrict__ aggv) {
  __shared__ float w2s[96 * 96];
  __shared__ float w2v[96 * 32];
  __shared__ float hb[8][8];
  __shared__ float sh1b[8][3];
  __shared__ float sh0b[8];
  __shared__ float tps[8][96];
  __shared__ float tpv[8][288];
  __shared__ float gat[8][32];

  const int t = threadIdx.x;
  for (int i = t; i < 96 * 96; i += 256) w2s[i] = W2s[i];
  for (int i = t; i < 96 * 32; i += 256) w2v[i] = W2v[i];

  const int l = t & 31;       // lane within edge (phase 1)
  const int el = t >> 5;      // edge slot 0..7
  const float isq96 = 0.10206207261596575f;  // 1/sqrt(96)

  const int nchunk = E / 8;   // 75000 exact
  for (int chunk = blockIdx.x; chunk < nchunk; chunk += gridDim.x) {
    __syncthreads();  // protect LDS scratch from previous chunk readers
    const int e = chunk * 8 + el;
    // ---- phase 1a: radial MLP hidden, sh staging ----
    if (l < 8) {
      float hh = 0.f;
#pragma unroll
      for (int r = 0; r < 8; r++) hh += emb[e * 8 + r] * Wm1[r * 8 + l];
      hb[el][l] = silu_f(hh);
    }
    if (l < 3) sh1b[el][l] = sh1[e * 3 + l];
    if (l == 3) sh0b[el] = sh0[e];
    __syncthreads();
    // ---- phase 1b: tensor product into LDS ----
    {
      const int src = eidx[e];
      const float s0v = sh0b[el];
      const float x0 = sh1b[el][0], x1 = sh1b[el][1], x2 = sh1b[el][2];
#pragma unroll
      for (int rep = 0; rep < 2; rep++) {
        const int u = l + rep * 32;
        float w0a = 0.f, w1a = 0.f;
#pragma unroll
        for (int h = 0; h < 8; h++) {
          float hv = hb[el][h];
          w0a += hv * Wm2[h * 192 + u];
          w1a += hv * Wm2[h * 192 + 64 + u];
        }
        const float ssu = s1[src * 64 + u];
        tps[el][u] = w0a * ssu * s0v;
        const float base = w1a * ssu;
        tpv[el][u * 3 + 0] = base * x0;
        tpv[el][u * 3 + 1] = base * x1;
        tpv[el][u * 3 + 2] = base * x2;
      }
      {
        const int u = l;  // 0..31
        float w1b = 0.f, w0b = 0.f;
#pragma unroll
        for (int h = 0; h < 8; h++) {
          float hv = hb[el][h];
          w1b += hv * Wm2[h * 192 + 128 + u];
          w0b += hv * Wm2[h * 192 + 160 + u];
        }
        const float va = v1[src * 96 + u * 3 + 0];
        const float vb = v1[src * 96 + u * 3 + 1];
        const float vc = v1[src * 96 + u * 3 + 2];
        tps[el][64 + u] = w0b * (va * x0 + vb * x1 + vc * x2);
        tpv[el][(64 + u) * 3 + 0] = w1b * va * s0v;
        tpv[el][(64 + u) * 3 + 1] = w1b * vb * s0v;
        tpv[el][(64 + u) * 3 + 2] = w1b * vc * s0v;
      }
    }
    __syncthreads();
    // ---- phase 2: m_s = tp_s @ W2s / sqrt(96); silu -> atomics; sigmoid -> gates ----
    const int jt = l;
    const int dst = eidx[E + e];
    {
      float a0 = 0.f, a1 = 0.f, a2 = 0.f;
#pragma unroll 8
      for (int k = 0; k < 96; k++) {
        const float tv = tps[el][k];
        a0 += tv * w2s[k * 96 + jt];
        a1 += tv * w2s[k * 96 + jt + 32];
        a2 += tv * w2s[k * 96 + jt + 64];
      }
      a0 *= isq96; a1 *= isq96; a2 *= isq96;
      atomicAdd(&aggs[dst * 64 + jt],      silu_f(a0));
      atomicAdd(&aggs[dst * 64 + jt + 32], silu_f(a1));
      gat[el][jt] = sigm_f(a2);
    }
    __syncthreads();
    // ---- phase 3: m_v = tp_v x W2v / sqrt(96) * gate -> atomics ----
    {
      const int p0 = jt, p1 = jt + 32, p2 = jt + 64;
      const int v0 = p0 / 3, c0 = p0 % 3;
      const int v1i = p1 / 3, c1 = p1 % 3;
      const int v2i = p2 / 3, c2 = p2 % 3;
      float b0 = 0.f, b1 = 0.f, b2 = 0.f;
#pragma unroll 8
      for (int u = 0; u < 96; u++) {
        const float* tr = &tpv[el][u * 3];
        b0 += tr[c0] * w2v[u * 32 + v0];
        b1 += tr[c1] * w2v[u * 32 + v1i];
        b2 += tr[c2] * w2v[u * 32 + v2i];
      }
      atomicAdd(&aggv[dst * 96 + p0], b0 * isq96 * gat[el][v0]);
      atomicAdd(&aggv[dst * 96 + p1], b1 * isq96 * gat[el][v1i]);
      atomicAdd(&aggv[dst * 96 + p2], b2 * isq96 * gat[el][v2i]);
    }
  }
}

// ---------------- Kernel C1: f_s = (agg_s*d0)@W3s/8 + sc_s/32 ; write out_s + gates ----------------
#define C1_NT 32
__global__ __launch_bounds__(256, 2)
void k_c1(const float* __restrict__ node_s, const float* __restrict__ attrs,
          const float* __restrict__ aggs, const float* __restrict__ Wt0,
          const float* __restrict__ W3s, const float* __restrict__ Wsc0,
          float* __restrict__ out, float* __restrict__ gates) {
  __shared__ float wch[6144];          // 64k x 96j chunk of Wsc0 (or W3s at the end)
  __shared__ float s_row[C1_NT][64];
  __shared__ float attr[C1_NT][16];
  __shared__ float t0[C1_NT][64];
  const int t = threadIdx.x;
  const int jt = t & 31;
  const int nt = t >> 5;               // 0..7
  const int npass = (N + C1_NT - 1) / C1_NT;
  for (int pass = blockIdx.x; pass < npass; pass += gridDim.x) {
    const int nbase = pass * C1_NT;
    __syncthreads();  // protect LDS from previous pass readers
    for (int i = t; i < C1_NT * 64; i += 256) {
      int nl = i >> 6, u = i & 63, n = nbase + nl;
      s_row[nl][u] = (n < N) ? node_s[n * 64 + u] : 0.f;
      t0[nl][u]   = (n < N) ? aggs[n * 64 + u] : 0.f;
    }
    for (int i = t; i < C1_NT * 16; i += 256) {
      int nl = i >> 4, a = i & 15, n = nbase + nl;
      attr[nl][a] = (n < N) ? attrs[n * 16 + a] : 0.f;
    }
    __syncthreads();
    // t0[u] = raw_agg * (attr . Wt0[u]) / (4*sqrt(12))
    for (int i = t; i < C1_NT * 64; i += 256) {
      int nl = i >> 6, u = i & 63;
      float d0 = 0.f;
#pragma unroll
      for (int a = 0; a < 16; a++) d0 += attr[nl][a] * Wt0[u * 16 + a];
      t0[nl][u] *= d0 * 0.07216878364870322f;
    }
    float acc[4][3] = {};
    for (int chunk = 0; chunk < 16; chunk++) {
      __syncthreads();
      for (int i = t; i < 6144; i += 256) wch[i] = Wsc0[chunk * 6144 + i];
      __syncthreads();
#pragma unroll
      for (int uu = 0; uu < 4; uu++) {
        const int u = chunk * 4 + uu;
        float s4[4];
#pragma unroll
        for (int nl = 0; nl < 4; nl++) s4[nl] = s_row[nt + nl * 8][u];
#pragma unroll
        for (int a = 0; a < 16; a++) {
          const int kl = uu * 16 + a;
          const float w0 = wch[kl * 96 + jt];
          const float w1 = wch[kl * 96 + jt + 32];
          const float w2 = wch[kl * 96 + jt + 64];
#pragma unroll
          for (int nl = 0; nl < 4; nl++) {
            const float z = s4[nl] * attr[nt + nl * 8][a];
            acc[nl][0] += z * w0; acc[nl][1] += z * w1; acc[nl][2] += z * w2;
          }
        }
      }
    }
    __syncthreads();
    for (int i = t; i < 6144; i += 256) wch[i] = W3s[i];  // 64x96
    __syncthreads();
    float facc[4][3] = {};
#pragma unroll 4
    for (int u = 0; u < 64; u++) {
      const float w0 = wch[u * 96 + jt];
      const float w1 = wch[u * 96 + jt + 32];
      const float w2 = wch[u * 96 + jt + 64];
#pragma unroll
      for (int nl = 0; nl < 4; nl++) {
        const float tv = t0[nt + nl * 8][u];
        facc[nl][0] += tv * w0; facc[nl][1] += tv * w1; facc[nl][2] += tv * w2;
      }
    }
#pragma unroll
    for (int nl = 0; nl < 4; nl++) {
      const int n = nbase + nt + nl * 8;
      if (n >= N) continue;
#pragma unroll
      for (int jo = 0; jo < 3; jo++) {
        const int j = jt + jo * 32;
        const float f = facc[nl][jo] * 0.125f + acc[nl][jo] * 0.03125f;
        if (j < 64) out[n * 160 + j] = silu_f(f);
        else        gates[n * 32 + (j - 64)] = sigm_f(f);
      }
    }
  }
}

// ---------------- Kernel C2: f_v = (agg_v*d1)@W3v/sqrt(32) + sc_v/sqrt(512), * gate ----------------
__global__ __launch_bounds__(256, 2)
void k_c2(const float* __restrict__ node_v, const float* __restrict__ attrs,
          const float* __restrict__ aggv, const float* __restrict__ Wt1,
          const float* __restrict__ W3v, const float* __restrict__ Wsc1,
          const float* __restrict__ gates, float* __restrict__ out) {
  __shared__ float wsc[4096];   // 8u x 16a x 32w chunk of Wsc1
  __shared__ float w3v[1024];
  __shared__ float nv[8][96];
  __shared__ float t1[8][96];
  __shared__ float attr[8][16];
  const int t = threadIdx.x;
  const int w = t & 31, nl = t >> 5;
  for (int i = t; i < 1024; i += 256) w3v[i] = W3v[i];
  for (int pass = blockIdx.x; pass < N / 8; pass += gridDim.x) {
    const int nbase = pass * 8;
    __syncthreads();  // protect LDS from previous pass readers (also fences w3v once)
    for (int i = t; i < 8 * 96; i += 256) {
      int n = i / 96, r = i % 96;
      nv[n][r] = node_v[(nbase + n) * 96 + r];
      t1[n][r] = aggv[(nbase + n) * 96 + r];
    }
    if (t < 128) attr[t >> 4][t & 15] = attrs[nbase * 16 + t];
    __syncthreads();
    {   // t1 *= d1 * 1/(4*sqrt(12))   (thread owns u=w for node nl)
      const int u = w;
      float d1 = 0.f;
#pragma unroll
      for (int a = 0; a < 16; a++) d1 += attr[nl][a] * Wt1[u * 16 + a];
      d1 *= 0.07216878364870322f;
      t1[nl][u * 3 + 0] *= d1; t1[nl][u * 3 + 1] *= d1; t1[nl][u * 3 + 2] *= d1;
    }
    float scv0 = 0.f, scv1 = 0.f, scv2 = 0.f;
    for (int cu = 0; cu < 4; cu++) {
      __syncthreads();
      for (int i = t; i < 4096; i += 256) wsc[i] = Wsc1[cu * 4096 + i];
      __syncthreads();
#pragma unroll
      for (int u8 = 0; u8 < 8; u8++) {
        const int u = cu * 8 + u8;
        float g = 0.f;
#pragma unroll
        for (int a = 0; a < 16; a++) g += attr[nl][a] * wsc[(u8 * 16 + a) * 32 + w];
        scv0 += nv[nl][u * 3 + 0] * g;
        scv1 += nv[nl][u * 3 + 1] * g;
        scv2 += nv[nl][u * 3 + 2] * g;
      }
    }
    float fv0 = 0.f, fv1 = 0.f, fv2 = 0.f;
#pragma unroll 8
    for (int u = 0; u < 32; u++) {
      const float wv = w3v[u * 32 + w];
      fv0 += t1[nl][u * 3 + 0] * wv;
      fv1 += t1[nl][u * 3 + 1] * wv;
      fv2 += t1[nl][u * 3 + 2] * wv;
    }
    const int n = nbase + nl;
    const float gate = gates[n * 32 + w];
    const float is32 = 0.17677669529663689f;   // 1/sqrt(32)
    const float is512 = 0.044194173824159216f; // 1/sqrt(512)
    out[n * 160 + 64 + w * 3 + 0] = (fv0 * is32 + scv0 * is512) * gate;
    out[n * 160 + 64 + w * 3 + 1] = (fv1 * is32 + scv1 * is512) * gate;
    out[n * 160 + 64 + w * 3 + 2] = (fv2 * is32 + scv2 * is512) * gate;
  }
}

extern "C" void kernel_launch(void* const* d_in, const int* in_sizes, int n_in,
                              void* d_out, int out_size, void* d_ws, size_t ws_size,
                              hipStream_t stream) {
  const float* node_s = (const float*)d_in[0];
  const float* node_v = (const float*)d_in[1];
  const float* attrs  = (const float*)d_in[2];
  const float* emb    = (const float*)d_in[3];
  const float* sh0    = (const float*)d_in[4];
  const float* sh1    = (const float*)d_in[5];
  const int*   eidx   = (const int*)d_in[6];
  const float* W1s    = (const float*)d_in[7];
  const float* W1v    = (const float*)d_in[8];
  const float* Wm1    = (const float*)d_in[9];
  const float* Wm2    = (const float*)d_in[10];
  const float* W2s    = (const float*)d_in[11];
  const float* W2v    = (const float*)d_in[12];
  const float* Wt0    = (const float*)d_in[13];
  const float* Wt1    = (const float*)d_in[14];
  const float* W3s    = (const float*)d_in[15];
  const float* W3v    = (const float*)d_in[16];
  const float* Wsc0   = (const float*)d_in[17];
  const float* Wsc1   = (const float*)d_in[18];

  float* ws   = (float*)d_ws;
  float* s1   = ws;                    // N*64
  float* v1   = ws + (size_t)N * 64;   // N*96
  float* aggs = ws + (size_t)N * 160;  // N*64 (zeroed)
  float* aggv = ws + (size_t)N * 224;  // N*96 (zeroed)
  float* gts  = ws + (size_t)N * 320;  // N*32

  hipMemsetAsync(aggs, 0, (size_t)N * 160 * sizeof(float), stream);
  k_lin1<<<1024, 256, 0, stream>>>(node_s, node_v, W1s, W1v, s1, v1);
  k_edge<<<1024, 256, 0, stream>>>(s1, v1, emb, sh0, sh1, eidx, Wm1, Wm2, W2s, W2v, aggs, aggv);
  k_c1<<<512, 256, 0, stream>>>(node_s, attrs, aggs, Wt0, W3s, Wsc0, (float*)d_out, gts);
  k_c2<<<512, 256, 0, stream>>>(node_v, attrs, aggv, Wt1, W3v, Wsc1, gts, (float*)d_out);
}

// Round 2
// 1467.264 us; speedup vs baseline: 1.3755x; 1.3755x over previous
//
#include <hip/hip_runtime.h>
#include <math.h>

#define N 50000
#define E 600000
#define EPB 16     // edges per block-pass
#define LDK 104    // padded K stride (bf16 elems), breaks LDS bank pattern, keeps 16B align

typedef __attribute__((ext_vector_type(8))) short short8;
typedef __attribute__((ext_vector_type(4))) float float4v;

__device__ __forceinline__ float silu_f(float x) { return x / (1.f + __expf(-x)); }
__device__ __forceinline__ float sigm_f(float x) { return 1.f / (1.f + __expf(-x)); }
__device__ __forceinline__ unsigned short f2bf(float f) {
  unsigned u = __float_as_uint(f);
  u += 0x7fff + ((u >> 16) & 1);   // RNE
  return (unsigned short)(u >> 16);
}

// ---------------- Kernel A: s1 = node_s@W1s/8 ; v1 = node_v x W1v /sqrt(32) ----------------
__global__ __launch_bounds__(256, 4)
void k_lin1(const float* __restrict__ node_s, const float* __restrict__ node_v,
            const float* __restrict__ W1s, const float* __restrict__ W1v,
            float* __restrict__ s1, float* __restrict__ v1) {
  __shared__ float w1s[64 * 64];
  __shared__ float w1v[32 * 32];
  for (int i = threadIdx.x; i < 64 * 64; i += 256) w1s[i] = W1s[i];
  for (int i = threadIdx.x; i < 32 * 32; i += 256) w1v[i] = W1v[i];
  __syncthreads();
  const float is_ns = 0.125f;
  const float is_nv = 0.17677669529663689f;
  int gtid = blockIdx.x * 256 + threadIdx.x;
  int stride = gridDim.x * 256;
  for (int i = gtid; i < N * 160; i += stride) {
    int n = i / 160, ch = i % 160;
    if (ch < 64) {
      const float* row = node_s + n * 64;
      float acc = 0.f;
#pragma unroll
      for (int u = 0; u < 64; u++) acc += row[u] * w1s[u * 64 + ch];
      s1[n * 64 + ch] = acc * is_ns;
    } else {
      int p = ch - 64, v = p / 3, c = p % 3;
      const float* row = node_v + n * 96;
      float acc = 0.f;
#pragma unroll
      for (int u = 0; u < 32; u++) acc += row[u * 3 + c] * w1v[u * 32 + v];
      v1[n * 96 + p] = acc * is_nv;
    }
  }
}

// ---------------- Kernel B: per-edge message via MFMA + scatter ----------------
__global__ __launch_bounds__(256, 3)
void k_edge(const float* __restrict__ s1, const float* __restrict__ v1,
            const float* __restrict__ emb, const float* __restrict__ sh0g,
            const float* __restrict__ sh1g, const int* __restrict__ eidx,
            const float* __restrict__ Wm1, const float* __restrict__ Wm2,
            const float* __restrict__ W2s, const float* __restrict__ W2v,
            float* __restrict__ aggs, float* __restrict__ aggv) {
  __shared__ unsigned short w2sT[96 * LDK];   // W2sT[j][k] bf16
  __shared__ unsigned short w2vT[32 * LDK];   // W2vT[v][k] bf16
  __shared__ float wm2t[192 * 8];             // Wm2T[col][h]
  __shared__ float wm1s[64];
  __shared__ unsigned short tps[EPB * LDK];         // [e][k] bf16
  __shared__ unsigned short tpv[EPB * 3 * LDK];     // [(e*3+c)][k] bf16
  __shared__ float gat[EPB][32];
  __shared__ float hb[EPB][8];
  __shared__ float embb[EPB * 8];
  __shared__ float sh1b[EPB][4];
  __shared__ float sh0b[EPB];
  __shared__ int ssrc[EPB];
  __shared__ int sdst[EPB];

  const int t = threadIdx.x;
  // one-time weight staging (transposed, bf16 for MFMA B-operands)
  for (int i = t; i < 96 * 96; i += 256) {
    int k = i / 96, j = i % 96;
    w2sT[j * LDK + k] = f2bf(W2s[i]);
  }
  for (int i = t; i < 96 * 32; i += 256) {
    int u = i / 32, v = i % 32;
    w2vT[v * LDK + u] = f2bf(W2v[i]);
  }
  for (int i = t; i < 192 * 8; i += 256) {
    int h = i / 192, c = i % 192;
    wm2t[c * 8 + h] = Wm2[i];
  }
  if (t < 64) wm1s[t] = Wm1[t];

  const int wave = t >> 6, lane = t & 63;
  const int lm = lane & 15, quad = lane >> 4;
  const float isq96 = 0.10206207261596575f;

  for (int pass = blockIdx.x; pass < E / EPB; pass += gridDim.x) {
    const int ebase = pass * EPB;
    __syncthreads();   // protect LDS scratch from previous pass readers
    // ---- stage per-edge small data (coalesced) ----
    if (t < EPB) ssrc[t] = eidx[ebase + t];
    else if (t < 2 * EPB) sdst[t - EPB] = eidx[E + ebase + (t - EPB)];
    else if (t < 3 * EPB) sh0b[t - 2 * EPB] = sh0g[ebase + (t - 2 * EPB)];
    if (t >= 64 && t < 64 + EPB * 3) { int i = t - 64; sh1b[i / 3][i % 3] = sh1g[ebase * 3 + i]; }
    if (t >= 128 && t < 128 + EPB * 8) embb[t - 128] = emb[ebase * 8 + (t - 128)];
    __syncthreads();
    // ---- radial MLP hidden ----
    if (t < EPB * 8) {
      int el = t >> 3, sub = t & 7;
      float acc = 0.f;
#pragma unroll
      for (int r = 0; r < 8; r++) acc += embb[el * 8 + r] * wm1s[r * 8 + sub];
      hb[el][sub] = silu_f(acc);
    }
    __syncthreads();
    // ---- build TPS / TPV (bf16, MFMA A-layout-friendly row-major) ----
    {
      const int el = t >> 4, sub = t & 15;     // 16 threads per edge
      const int src = ssrc[el];
      const float s0v = sh0b[el];
      const float x0 = sh1b[el][0], x1 = sh1b[el][1], x2 = sh1b[el][2];
      float hr[8];
#pragma unroll
      for (int h = 0; h < 8; h++) hr[h] = hb[el][h];
      // scalar-input paths: u = sub*4 + i
      const float4v ss = *(const float4v*)&s1[src * 64 + sub * 4];
      unsigned short tsv[4], tvv[3][4];
#pragma unroll
      for (int i = 0; i < 4; i++) {
        const int u = sub * 4 + i;
        float w0a = 0.f, w1a = 0.f;
#pragma unroll
        for (int h = 0; h < 8; h++) {
          w0a += hr[h] * wm2t[u * 8 + h];
          w1a += hr[h] * wm2t[(64 + u) * 8 + h];
        }
        const float ssu = ss[i];
        tsv[i] = f2bf(w0a * ssu * s0v);
        const float base = w1a * ssu;
        tvv[0][i] = f2bf(base * x0);
        tvv[1][i] = f2bf(base * x1);
        tvv[2][i] = f2bf(base * x2);
      }
      *(uint2*)&tps[el * LDK + sub * 4] = *(uint2*)tsv;
#pragma unroll
      for (int c = 0; c < 3; c++)
        *(uint2*)&tpv[(el * 3 + c) * LDK + sub * 4] = *(uint2*)tvv[c];
      // vector-input paths: u2 = sub*2 + i2
      const float2* vp = (const float2*)&v1[src * 96 + sub * 6];
      const float2 va = vp[0], vb = vp[1], vc = vp[2];
      const float v6[6] = {va.x, va.y, vb.x, vb.y, vc.x, vc.y};
      unsigned short ts2[2], tv2[3][2];
#pragma unroll
      for (int i2 = 0; i2 < 2; i2++) {
        const int u2 = sub * 2 + i2;
        float w1b = 0.f, w0b = 0.f;
#pragma unroll
        for (int h = 0; h < 8; h++) {
          w1b += hr[h] * wm2t[(128 + u2) * 8 + h];
          w0b += hr[h] * wm2t[(160 + u2) * 8 + h];
        }
        const float vx = v6[i2 * 3 + 0], vy = v6[i2 * 3 + 1], vz = v6[i2 * 3 + 2];
        ts2[i2] = f2bf(w0b * (vx * x0 + vy * x1 + vz * x2));
        tv2[0][i2] = f2bf(w1b * vx * s0v);
        tv2[1][i2] = f2bf(w1b * vy * s0v);
        tv2[2][i2] = f2bf(w1b * vz * s0v);
      }
      *(unsigned*)&tps[el * LDK + 64 + sub * 2] = *(unsigned*)ts2;
#pragma unroll
      for (int c = 0; c < 3; c++)
        *(unsigned*)&tpv[(el * 3 + c) * LDK + 64 + sub * 2] = *(unsigned*)tv2[c];
    }
    __syncthreads();
    // ---- GEMM1: m_s[16][96] = TPS @ W2s ;  silu -> atomics, sigmoid -> gates ----
    {
      short8 afr[3];
#pragma unroll
      for (int kk = 0; kk < 3; kk++)
        afr[kk] = *(const short8*)&tps[lm * LDK + kk * 32 + quad * 8];
      for (int nt = wave; nt < 6; nt += 4) {
        float4v acc = {0.f, 0.f, 0.f, 0.f};
#pragma unroll
        for (int kk = 0; kk < 3; kk++) {
          short8 bfr = *(const short8*)&w2sT[(nt * 16 + lm) * LDK + kk * 32 + quad * 8];
          acc = __builtin_amdgcn_mfma_f32_16x16x32_bf16(afr[kk], bfr, acc, 0, 0, 0);
        }
        const int j = nt * 16 + lm;
#pragma unroll
        for (int reg = 0; reg < 4; reg++) {
          const int e = quad * 4 + reg;
          const float val = acc[reg] * isq96;
          if (j < 64) atomicAdd(&aggs[(size_t)sdst[e] * 64 + j], silu_f(val));
          else gat[e][j - 64] = sigm_f(val);
        }
      }
    }
    __syncthreads();
    // ---- GEMM2: m_v[48][32] = TPV @ W2v ; gate -> atomics ----
    for (int tile = wave; tile < 6; tile += 4) {
      const int mt = tile >> 1, nt = tile & 1;
      float4v acc = {0.f, 0.f, 0.f, 0.f};
#pragma unroll
      for (int kk = 0; kk < 3; kk++) {
        short8 a = *(const short8*)&tpv[(mt * 16 + lm) * LDK + kk * 32 + quad * 8];
        short8 b = *(const short8*)&w2vT[(nt * 16 + lm) * LDK + kk * 32 + quad * 8];
        acc = __builtin_amdgcn_mfma_f32_16x16x32_bf16(a, b, acc, 0, 0, 0);
      }
      const int v = nt * 16 + lm;
#pragma unroll
      for (int reg = 0; reg < 4; reg++) {
        const int r = mt * 16 + quad * 4 + reg;
        const int e = (r * 171) >> 9, c = r - 3 * e;   // r/3, r%3 for r<512
        atomicAdd(&aggv[(size_t)sdst[e] * 96 + v * 3 + c], acc[reg] * isq96 * gat[e][v]);
      }
    }
  }
}

// ---------------- Kernel C1: f_s = (agg_s*d0)@W3s/8 + sc_s/32 ; write out_s + gates ----------------
#define C1_NT 32
__global__ __launch_bounds__(256, 2)
void k_c1(const float* __restrict__ node_s, const float* __restrict__ attrs,
          const float* __restrict__ aggs, const float* __restrict__ Wt0,
          const float* __restrict__ W3s, const float* __restrict__ Wsc0,
          float* __restrict__ out, float* __restrict__ gates) {
  __shared__ float wch[6144];
  __shared__ float s_row[C1_NT][64];
  __shared__ float attr[C1_NT][16];
  __shared__ float t0[C1_NT][64];
  const int t = threadIdx.x;
  const int jt = t & 31;
  const int nt = t >> 5;
  const int npass = (N + C1_NT - 1) / C1_NT;
  for (int pass = blockIdx.x; pass < npass; pass += gridDim.x) {
    const int nbase = pass * C1_NT;
    __syncthreads();
    for (int i = t; i < C1_NT * 64; i += 256) {
      int nl = i >> 6, u = i & 63, n = nbase + nl;
      s_row[nl][u] = (n < N) ? node_s[n * 64 + u] : 0.f;
      t0[nl][u]   = (n < N) ? aggs[n * 64 + u] : 0.f;
    }
    for (int i = t; i < C1_NT * 16; i += 256) {
      int nl = i >> 4, a = i & 15, n = nbase + nl;
      attr[nl][a] = (n < N) ? attrs[n * 16 + a] : 0.f;
    }
    __syncthreads();
    for (int i = t; i < C1_NT * 64; i += 256) {
      int nl = i >> 6, u = i & 63;
      float d0 = 0.f;
#pragma unroll
      for (int a = 0; a < 16; a++) d0 += attr[nl][a] * Wt0[u * 16 + a];
      t0[nl][u] *= d0 * 0.07216878364870322f;
    }
    float acc[4][3] = {};
    for (int chunk = 0; chunk < 16; chunk++) {
      __syncthreads();
      for (int i = t; i < 6144; i += 256) wch[i] = Wsc0[chunk * 6144 + i];
      __syncthreads();
#pragma unroll
      for (int uu = 0; uu < 4; uu++) {
        const int u = chunk * 4 + uu;
        float s4[4];
#pragma unroll
        for (int nl = 0; nl < 4; nl++) s4[nl] = s_row[nt + nl * 8][u];
#pragma unroll
        for (int a = 0; a < 16; a++) {
          const int kl = uu * 16 + a;
          const float w0 = wch[kl * 96 + jt];
          const float w1 = wch[kl * 96 + jt + 32];
          const float w2 = wch[kl * 96 + jt + 64];
#pragma unroll
          for (int nl = 0; nl < 4; nl++) {
            const float z = s4[nl] * attr[nt + nl * 8][a];
            acc[nl][0] += z * w0; acc[nl][1] += z * w1; acc[nl][2] += z * w2;
          }
        }
      }
    }
    __syncthreads();
    for (int i = t; i < 6144; i += 256) wch[i] = W3s[i];
    __syncthreads();
    float facc[4][3] = {};
#pragma unroll 4
    for (int u = 0; u < 64; u++) {
      const float w0 = wch[u * 96 + jt];
      const float w1 = wch[u * 96 + jt + 32];
      const float w2 = wch[u * 96 + jt + 64];
#pragma unroll
      for (int nl = 0; nl < 4; nl++) {
        const float tv = t0[nt + nl * 8][u];
        facc[nl][0] += tv * w0; facc[nl][1] += tv * w1; facc[nl][2] += tv * w2;
      }
    }
#pragma unroll
    for (int nl = 0; nl < 4; nl++) {
      const int n = nbase + nt + nl * 8;
      if (n >= N) continue;
#pragma unroll
      for (int jo = 0; jo < 3; jo++) {
        const int j = jt + jo * 32;
        const float f = facc[nl][jo] * 0.125f + acc[nl][jo] * 0.03125f;
        if (j < 64) out[n * 160 + j] = silu_f(f);
        else        gates[n * 32 + (j - 64)] = sigm_f(f);
      }
    }
  }
}

// ---------------- Kernel C2: f_v = (agg_v*d1)@W3v/sqrt(32) + sc_v/sqrt(512), * gate ----------------
__global__ __launch_bounds__(256, 2)
void k_c2(const float* __restrict__ node_v, const float* __restrict__ attrs,
          const float* __restrict__ aggv, const float* __restrict__ Wt1,
          const float* __restrict__ W3v, const float* __restrict__ Wsc1,
          const float* __restrict__ gates, float* __restrict__ out) {
  __shared__ float wsc[4096];
  __shared__ float w3v[1024];
  __shared__ float nv[8][96];
  __shared__ float t1[8][96];
  __shared__ float attr[8][16];
  const int t = threadIdx.x;
  const int w = t & 31, nl = t >> 5;
  for (int i = t; i < 1024; i += 256) w3v[i] = W3v[i];
  for (int pass = blockIdx.x; pass < N / 8; pass += gridDim.x) {
    const int nbase = pass * 8;
    __syncthreads();
    for (int i = t; i < 8 * 96; i += 256) {
      int n = i / 96, r = i % 96;
      nv[n][r] = node_v[(nbase + n) * 96 + r];
      t1[n][r] = aggv[(nbase + n) * 96 + r];
    }
    if (t < 128) attr[t >> 4][t & 15] = attrs[nbase * 16 + t];
    __syncthreads();
    {
      const int u = w;
      float d1 = 0.f;
#pragma unroll
      for (int a = 0; a < 16; a++) d1 += attr[nl][a] * Wt1[u * 16 + a];
      d1 *= 0.07216878364870322f;
      t1[nl][u * 3 + 0] *= d1; t1[nl][u * 3 + 1] *= d1; t1[nl][u * 3 + 2] *= d1;
    }
    float scv0 = 0.f, scv1 = 0.f, scv2 = 0.f;
    for (int cu = 0; cu < 4; cu++) {
      __syncthreads();
      for (int i = t; i < 4096; i += 256) wsc[i] = Wsc1[cu * 4096 + i];
      __syncthreads();
#pragma unroll
      for (int u8 = 0; u8 < 8; u8++) {
        const int u = cu * 8 + u8;
        float g = 0.f;
#pragma unroll
        for (int a = 0; a < 16; a++) g += attr[nl][a] * wsc[(u8 * 16 + a) * 32 + w];
        scv0 += nv[nl][u * 3 + 0] * g;
        scv1 += nv[nl][u * 3 + 1] * g;
        scv2 += nv[nl][u * 3 + 2] * g;
      }
    }
    float fv0 = 0.f, fv1 = 0.f, fv2 = 0.f;
#pragma unroll 8
    for (int u = 0; u < 32; u++) {
      const float wv = w3v[u * 32 + w];
      fv0 += t1[nl][u * 3 + 0] * wv;
      fv1 += t1[nl][u * 3 + 1] * wv;
      fv2 += t1[nl][u * 3 + 2] * wv;
    }
    const int n = nbase + nl;
    const float gate = gates[n * 32 + w];
    const float is32 = 0.17677669529663689f;
    const float is512 = 0.044194173824159216f;
    out[n * 160 + 64 + w * 3 + 0] = (fv0 * is32 + scv0 * is512) * gate;
    out[n * 160 + 64 + w * 3 + 1] = (fv1 * is32 + scv1 * is512) * gate;
    out[n * 160 + 64 + w * 3 + 2] = (fv2 * is32 + scv2 * is512) * gate;
  }
}

extern "C" void kernel_launch(void* const* d_in, const int* in_sizes, int n_in,
                              void* d_out, int out_size, void* d_ws, size_t ws_size,
                              hipStream_t stream) {
  const float* node_s = (const float*)d_in[0];
  const float* node_v = (const float*)d_in[1];
  const float* attrs  = (const float*)d_in[2];
  const float* emb    = (const float*)d_in[3];
  const float* sh0    = (const float*)d_in[4];
  const float* sh1    = (const float*)d_in[5];
  const int*   eidx   = (const int*)d_in[6];
  const float* W1s    = (const float*)d_in[7];
  const float* W1v    = (const float*)d_in[8];
  const float* Wm1    = (const float*)d_in[9];
  const float* Wm2    = (const float*)d_in[10];
  const float* W2s    = (const float*)d_in[11];
  const float* W2v    = (const float*)d_in[12];
  const float* Wt0    = (const float*)d_in[13];
  const float* Wt1    = (const float*)d_in[14];
  const float* W3s    = (const float*)d_in[15];
  const float* W3v    = (const float*)d_in[16];
  const float* Wsc0   = (const float*)d_in[17];
  const float* Wsc1   = (const float*)d_in[18];

  float* ws   = (float*)d_ws;
  float* s1   = ws;
  float* v1   = ws + (size_t)N * 64;
  float* aggs = ws + (size_t)N * 160;
  float* aggv = ws + (size_t)N * 224;
  float* gts  = ws + (size_t)N * 320;

  hipMemsetAsync(aggs, 0, (size_t)N * 160 * sizeof(float), stream);
  k_lin1<<<1024, 256, 0, stream>>>(node_s, node_v, W1s, W1v, s1, v1);
  k_edge<<<768, 256, 0, stream>>>(s1, v1, emb, sh0, sh1, eidx, Wm1, Wm2, W2s, W2v, aggs, aggv);
  k_c1<<<512, 256, 0, stream>>>(node_s, attrs, aggs, Wt0, W3s, Wsc0, (float*)d_out, gts);
  k_c2<<<512, 256, 0, stream>>>(node_v, attrs, aggv, Wt1, W3v, Wsc1, gts, (float*)d_out);
}